// Round 13
// baseline (162.652 us; speedup 1.0000x reference)
//
#include <hip/hip_runtime.h>
#include <math.h>

#define D 1024
#define S 8192
#define B 8
#define H 16
#define NROWS (B * S)
#define EPS_LN 1e-5f

typedef _Float16 h2 __attribute__((ext_vector_type(2)));
typedef __fp16 half8 __attribute__((ext_vector_type(8)));
typedef float f32x4 __attribute__((ext_vector_type(4)));

__device__ __forceinline__ float wred_sum(float v) {
#pragma unroll
  for (int m = 1; m < 64; m <<= 1) v += __shfl_xor(v, m, 64);
  return v;
}
__device__ __forceinline__ h2 pkh(float a, float b) {
#if __has_builtin(__builtin_amdgcn_cvt_pkrtz)
  return __builtin_bit_cast(h2, __builtin_amdgcn_cvt_pkrtz(a, b));
#else
  h2 r; r.x = (_Float16)a; r.y = (_Float16)b; return r;
#endif
}
__device__ __forceinline__ float fdot2(h2 a, h2 b, float c) {
#if __has_builtin(__builtin_amdgcn_fdot2)
  typedef __fp16 fp16v2 __attribute__((ext_vector_type(2)));
  return __builtin_amdgcn_fdot2(__builtin_bit_cast(fp16v2, a),
                                __builtin_bit_cast(fp16v2, b), c, false);
#else
  return c + (float)a.x * (float)b.x + (float)a.y * (float)b.y;
#endif
}
__device__ __forceinline__ h2 bch(unsigned int u) { return __builtin_bit_cast(h2, u); }
__device__ __forceinline__ unsigned int hbits(h2 v) {
  return __builtin_bit_cast(unsigned int, v);
}

// ---------- LN over one 1024-row per block (256 thr) ----------
__global__ void k_ln256(const float* __restrict__ in, const float* __restrict__ g,
                        const float* __restrict__ bb, float* __restrict__ out) {
  const int b = blockIdx.x, t = threadIdx.x;
  float4 v = ((const float4*)(in + (size_t)b * D))[t];
  float s = v.x + v.y + v.z + v.w;
  float s2 = fmaf(v.x, v.x, fmaf(v.y, v.y, fmaf(v.z, v.z, v.w * v.w)));
  __shared__ float red[8];
  float ws = wred_sum(s), ws2 = wred_sum(s2);
  const int lane = t & 63, wv = t >> 6;
  if (!lane) { red[wv] = ws; red[wv + 4] = ws2; }
  __syncthreads();
  ws = red[0] + red[1] + red[2] + red[3];
  ws2 = red[4] + red[5] + red[6] + red[7];
  const float m = ws * (1.f / D);
  const float rs = rsqrtf(ws2 * (1.f / D) - m * m + EPS_LN);
  const float4 gg = ((const float4*)g)[t], bv = ((const float4*)bb)[t];
  float4 o;
  o.x = (v.x - m) * rs * gg.x + bv.x;
  o.y = (v.y - m) * rs * gg.y + bv.y;
  o.z = (v.z - m) * rs * gg.z + bv.z;
  o.w = (v.w - m) * rs * gg.w + bv.w;
  ((float4*)(out + (size_t)b * D))[t] = o;
}

// ---------- fused: query LN (replicated) + q-projection ----------
__global__ void k_qln(const float* __restrict__ query, const float* __restrict__ ng,
                      const float* __restrict__ nb, const float* __restrict__ Wq,
                      const float* __restrict__ bq, float* __restrict__ qv) {
  __shared__ float qn[D];
  __shared__ float red[8];
  const int t = threadIdx.x, lane = t & 63, wv = t >> 6;
  float4 v = ((const float4*)query)[t];
  float s = v.x + v.y + v.z + v.w;
  float s2 = fmaf(v.x, v.x, fmaf(v.y, v.y, fmaf(v.z, v.z, v.w * v.w)));
  float ws = wred_sum(s), ws2 = wred_sum(s2);
  if (!lane) { red[wv] = ws; red[wv + 4] = ws2; }
  __syncthreads();
  ws = red[0] + red[1] + red[2] + red[3];
  ws2 = red[4] + red[5] + red[6] + red[7];
  const float m = ws * (1.f / D);
  const float rs = rsqrtf(ws2 * (1.f / D) - m * m + EPS_LN);
  const float4 gg = ((const float4*)ng)[t], bv = ((const float4*)nb)[t];
  float4 o;
  o.x = (v.x - m) * rs * gg.x + bv.x;
  o.y = (v.y - m) * rs * gg.y + bv.y;
  o.z = (v.z - m) * rs * gg.z + bv.z;
  o.w = (v.w - m) * rs * gg.w + bv.w;
  ((float4*)qn)[t] = o;
  __syncthreads();
  const int j = blockIdx.x * 4 + wv;
  const float4* wr = (const float4*)(Wq + (size_t)j * D);
  float acc = 0.f;
#pragma unroll
  for (int k = 0; k < 4; k++) {
    float4 a = ((const float4*)qn)[lane + 64 * k], w = wr[lane + 64 * k];
    acc = fmaf(a.x, w.x, acc); acc = fmaf(a.y, w.y, acc);
    acc = fmaf(a.z, w.z, acc); acc = fmaf(a.w, w.w, acc);
  }
  acc = wred_sum(acc);
  if (!lane) qv[j] = acc + bq[j];
}

// ---------- fused: weight scalars + g-tables + zero hc/Cbuf ----------
__global__ void k_prep0G(const float* __restrict__ g, const float* __restrict__ b,
                         float* __restrict__ sconst, uint4* __restrict__ gt,
                         uint4* __restrict__ g2t, uint4* __restrict__ gbt,
                         float* __restrict__ hc, float* __restrict__ Cbuf) {
  const int t = threadIdx.x;
  float4 gv = ((const float4*)g)[t], bv = ((const float4*)b)[t];
  float sg = gv.x + gv.y + gv.z + gv.w;
  float sb = bv.x + bv.y + bv.z + bv.w;
  float sbb = bv.x * bv.x + bv.y * bv.y + bv.z * bv.z + bv.w * bv.w;
  float sgb = gv.x * bv.x + gv.y * bv.y + gv.z * bv.z + gv.w * bv.w;
  float sgg = gv.x * gv.x + gv.y * gv.y + gv.z * gv.z + gv.w * gv.w;
  __shared__ float red[4][5];
  sg = wred_sum(sg); sb = wred_sum(sb); sbb = wred_sum(sbb);
  sgb = wred_sum(sgb); sgg = wred_sum(sgg);
  const int lane = t & 63, wv = t >> 6;
  if (!lane) { red[wv][0] = sg; red[wv][1] = sb; red[wv][2] = sbb; red[wv][3] = sgb; red[wv][4] = sgg; }
  __syncthreads();
  if (t < 5) sconst[t] = red[0][t] + red[1][t] + red[2][t] + red[3][t];
  if (t < 16) ((float4*)hc)[t] = make_float4(0.f, 0.f, 0.f, 0.f);
  if (t < 128) ((float4*)Cbuf)[t] = make_float4(0.f, 0.f, 0.f, 0.f);
  if (t < 128) {
    const int grp = t;
    const int k0 = (grp >> 2) * 32 + (grp & 3) * 8;
    unsigned int a[4], bb2[4], c[4];
#pragma unroll
    for (int p = 0; p < 4; p++) {
      const int k = k0 + 2 * p;
      const float g0 = g[k], g1v = g[k + 1];
      const float b0 = b[k], b1v = b[k + 1];
      a[p] = hbits(pkh(g0, g1v));
      bb2[p] = hbits(pkh(g0 * g0, g1v * g1v));
      c[p] = hbits(pkh(g0 * b0, g1v * b1v));
    }
    gt[grp] = make_uint4(a[0], a[1], a[2], a[3]);
    g2t[grp] = make_uint4(bb2[0], bb2[1], bb2[2], bb2[3]);
    gbt[grp] = make_uint4(c[0], c[1], c[2], c[3]);
  }
}

// ---------- per (head, quarter): U-proj slice + hc partials (atomic) + B1 frags ----
__global__ void k_uprep64(const float* __restrict__ qv, const float* __restrict__ Wk,
                          const float* __restrict__ g1, const float* __restrict__ b1,
                          const float* __restrict__ kgw, const float* __restrict__ kbw,
                          float* __restrict__ hc, uint4* __restrict__ B1) {
  __shared__ float sUf[256];
  __shared__ float qh[64];
  __shared__ float red[4][4];
  const int h = blockIdx.x >> 2, q = blockIdx.x & 3, t = threadIdx.x;
  if (t < 64) qh[t] = qv[h * 64 + t];
  __syncthreads();
  const int d = q * 256 + t;
  float acc = 0.f;
#pragma unroll 4
  for (int e = 0; e < 64; e++)
    acc = fmaf(qh[e], Wk[(size_t)(h * 64 + e) * D + d], acc);
  acc *= 0.125f;  // 1/sqrt(64)
  sUf[t] = acc;
  const float gv = g1[d], bv = b1[d], kgv = kgw[d], kbv = kbw[d];
  float p2 = acc * kgv * bv;
  float p3 = acc * gv * kgv;
  float p4 = acc * kgv;
  float p5 = acc * kbv;
  p2 = wred_sum(p2); p3 = wred_sum(p3); p4 = wred_sum(p4); p5 = wred_sum(p5);
  const int lane = t & 63, wv = t >> 6;
  if (!lane) { red[wv][0] = p2; red[wv][1] = p3; red[wv][2] = p4; red[wv][3] = p5; }
  __syncthreads();
  if (t < 4)
    atomicAdd(&hc[t * 16 + h], red[0][t] + red[1][t] + red[2][t] + red[3][t]);
  if (t < 32) {
    const int grp = q * 32 + t;
    const int k0 = (grp >> 2) * 32 + (grp & 3) * 8;  // global dim base
    const int kl = k0 - q * 256;                      // local 0..255
    unsigned int wv2[4];
#pragma unroll
    for (int p = 0; p < 4; p++) {
      const int k = kl + 2 * p, kg2 = k0 + 2 * p;
      const float e0 = sUf[k] * g1[kg2] * kgw[kg2];
      const float e1 = sUf[k + 1] * g1[kg2 + 1] * kgw[kg2 + 1];
      wv2[p] = hbits(pkh(e0, e1));
    }
    B1[grp * 16 + h] = make_uint4(wv2[0], wv2[1], wv2[2], wv2[3]);
  }
}

// ---------- SINGLE PASS over x: scores (MFMA) + stats + online exp + PV (MFMA) ----
// 49 KB LDS -> 3 blocks/CU; 1 barrier/iter (double-buffered exchange); PV re-reads
// x from global (L2-hot) with dim mapping col*16+c for vectorized loads.
__global__ __launch_bounds__(256, 3) void k_fused(
    const float* __restrict__ x, const uint4* __restrict__ B1,
    const uint4* __restrict__ gt, const uint4* __restrict__ g2t,
    const uint4* __restrict__ gbt, const float* __restrict__ hc,
    const float* __restrict__ sconst, float* __restrict__ part,
    float* __restrict__ Cbuf, int niter, int bpb) {
  __shared__ __align__(16) uint4 sB[2048];                     // 32 KB
  __shared__ __align__(16) uint4 sg[128], sg2[128], sgb[128];  // 6 KB
  __shared__ __align__(16) f32x4 sred[2][4][64];               // 8 KB
  __shared__ float stat[2][4][16][6];                          // 3 KB
  for (int i = threadIdx.x; i < 2048; i += 256) sB[i] = B1[i];
  if (threadIdx.x < 128) {
    sg[threadIdx.x] = gt[threadIdx.x];
    sg2[threadIdx.x] = g2t[threadIdx.x];
    sgb[threadIdx.x] = gbt[threadIdx.x];
  }
  __syncthreads();
  const int lane = threadIdx.x & 63, w = threadIdx.x >> 6;
  const int col = lane & 15, kg = lane >> 4;
  const float c2 = hc[col], c3 = hc[16 + col], c4 = hc[32 + col], c5 = hc[48 + col];
  const float Sg1 = sconst[0], Sb1 = sconst[1], Sbbc = sconst[2];
  const float Sgbc = sconst[3], Sggc = sconst[4];
  const h2 one = {(_Float16)1.f, (_Float16)1.f};
  f32x4 accpv[16];
#pragma unroll
  for (int c = 0; c < 16; c++) accpv[c] = (f32x4){0.f, 0.f, 0.f, 0.f};
  float dh0 = 0.f, dh1 = 0.f, dh2 = 0.f, dh3 = 0.f;
  const int rbase = blockIdx.x * (16 * niter);
#pragma unroll 1
  for (int it = 0; it < niter; it++) {
    const int p = it & 1;
    const int r0 = rbase + it * 16;
    const float* xrow = x + (size_t)(r0 + col) * D + w * 256 + kg * 8;
    f32x4 sacc = {0.f, 0.f, 0.f, 0.f};
    float S0 = 0, S1 = 0, Sa = 0, Sb = 0, Sc = 0, Sd = 0;
#pragma unroll
    for (int ks = 0; ks < 8; ks++) {
      const float4 A0 = *(const float4*)(xrow + ks * 32);
      const float4 A1 = *(const float4*)(xrow + ks * 32 + 4);
      const h2 a0 = pkh(A0.x, A0.y), a1 = pkh(A0.z, A0.w);
      const h2 a2 = pkh(A1.x, A1.y), a3 = pkh(A1.z, A1.w);
      const int gidx = (w * 8 + ks) * 4 + kg;
      const uint4 bu = sB[gidx * 16 + col];
      const uint4 gu = sg[gidx], g2u = sg2[gidx], gbu = sgb[gidx];
      S0 = fdot2(a0, one, S0); S0 = fdot2(a1, one, S0);
      S0 = fdot2(a2, one, S0); S0 = fdot2(a3, one, S0);
      S1 = fdot2(a0, a0, S1); S1 = fdot2(a1, a1, S1);
      S1 = fdot2(a2, a2, S1); S1 = fdot2(a3, a3, S1);
      const h2 g0 = bch(gu.x), g1p = bch(gu.y), g2p = bch(gu.z), g3p = bch(gu.w);
      Sa = fdot2(g0, a0, Sa); Sa = fdot2(g1p, a1, Sa);
      Sa = fdot2(g2p, a2, Sa); Sa = fdot2(g3p, a3, Sa);
      const h2 G0 = bch(g2u.x), G1 = bch(g2u.y), G2 = bch(g2u.z), G3 = bch(g2u.w);
      Sb = fdot2(G0, a0, Sb); Sb = fdot2(G1, a1, Sb);
      Sb = fdot2(G2, a2, Sb); Sb = fdot2(G3, a3, Sb);
      Sc = fdot2(G0, a0 * a0, Sc); Sc = fdot2(G1, a1 * a1, Sc);
      Sc = fdot2(G2, a2 * a2, Sc); Sc = fdot2(G3, a3 * a3, Sc);
      const h2 Q0 = bch(gbu.x), Q1 = bch(gbu.y), Q2 = bch(gbu.z), Q3 = bch(gbu.w);
      Sd = fdot2(Q0, a0, Sd); Sd = fdot2(Q1, a1, Sd);
      Sd = fdot2(Q2, a2, Sd); Sd = fdot2(Q3, a3, Sd);
      union { h2 pp[4]; half8 v; } ua;
      ua.pp[0] = a0; ua.pp[1] = a1; ua.pp[2] = a2; ua.pp[3] = a3;
      sacc = __builtin_amdgcn_mfma_f32_16x16x32_f16(
          ua.v, __builtin_bit_cast(half8, bu), sacc, 0, 0, 0);
    }
#pragma unroll
    for (int m = 16; m < 64; m <<= 1) {
      S0 += __shfl_xor(S0, m, 64); S1 += __shfl_xor(S1, m, 64);
      Sa += __shfl_xor(Sa, m, 64); Sb += __shfl_xor(Sb, m, 64);
      Sc += __shfl_xor(Sc, m, 64); Sd += __shfl_xor(Sd, m, 64);
    }
    if (lane < 16) {
      stat[p][w][lane][0] = S0; stat[p][w][lane][1] = S1; stat[p][w][lane][2] = Sa;
      stat[p][w][lane][3] = Sb; stat[p][w][lane][4] = Sc; stat[p][w][lane][5] = Sd;
    }
    sred[p][w][lane] = sacc;
    __syncthreads();
    f32x4 full = sred[p][0][lane];
    full += sred[p][1][lane]; full += sred[p][2][lane]; full += sred[p][3][lane];
    float T0 = 0, T1v = 0, Ta = 0, Tb = 0, Tc = 0, Td = 0;
#pragma unroll
    for (int ww = 0; ww < 4; ww++) {
      T0 += stat[p][ww][col][0]; T1v += stat[p][ww][col][1]; Ta += stat[p][ww][col][2];
      Tb += stat[p][ww][col][3]; Tc += stat[p][ww][col][4]; Td += stat[p][ww][col][5];
    }
    const float m1 = T0 * (1.f / D);
    const float rs1 = rsqrtf(T1v * (1.f / D) - m1 * m1 + EPS_LN);
    const float m2 = (rs1 * (Ta - m1 * Sg1) + Sb1) * (1.f / D);
    const float sxn2 = rs1 * rs1 * Tc + 2.f * rs1 * (Td - m1 * rs1 * Tb) +
                       (Sbbc - 2.f * m1 * rs1 * Sgbc + m1 * m1 * rs1 * rs1 * Sggc);
    const float rs2 = rsqrtf(sxn2 * (1.f / D) - m2 * m2 + EPS_LN);
    const float v1 = rs1 * rs2, v2 = v1 * m1, v3 = rs2, v4 = rs2 * m2;
    float ap_[4];
#pragma unroll
    for (int j = 0; j < 4; j++) {
      const int rj = kg * 4 + j;
      const float w1 = __shfl(v1, rj, 64), w2 = __shfl(v2, rj, 64);
      const float w3 = __shfl(v3, rj, 64), w4 = __shfl(v4, rj, 64);
      const float s = w1 * full[j] - w2 * c3 + w3 * c2 - w4 * c4 + c5;
      const float e = __expf(s);
      ap_[j] = e * w1;
      if (w == 0) { dh0 += e; dh1 += e * w3; dh2 += e * w2; dh3 += e * w4; }
    }
    union { h2 pp[4]; half8 v; } ap;
    ap.pp[0] = pkh(ap_[0], ap_[1]); ap.pp[1] = pkh(ap_[2], ap_[3]);
    ap.pp[2] = bch(0u); ap.pp[3] = bch(0u);
    // PV: re-read x from global (L2-hot); dims col*16 + c; rows kg*4+{0..3}
    const float* xpv = x + (size_t)(r0 + kg * 4) * D + w * 256 + col * 16;
#pragma unroll
    for (int cg = 0; cg < 4; cg++) {
      const float4 xA = *(const float4*)(xpv + cg * 4);
      const float4 xB = *(const float4*)(xpv + D + cg * 4);
      const float4 xC = *(const float4*)(xpv + 2 * D + cg * 4);
      const float4 xD = *(const float4*)(xpv + 3 * D + cg * 4);
      const float fA[4] = {xA.x, xA.y, xA.z, xA.w};
      const float fB[4] = {xB.x, xB.y, xB.z, xB.w};
      const float fC[4] = {xC.x, xC.y, xC.z, xC.w};
      const float fD[4] = {xD.x, xD.y, xD.z, xD.w};
#pragma unroll
      for (int e2 = 0; e2 < 4; e2++) {
        const int c = cg * 4 + e2;
        union { unsigned int u[4]; half8 v; } bb;
        bb.u[0] = hbits(pkh(fA[e2], fB[e2]));
        bb.u[1] = hbits(pkh(fC[e2], fD[e2]));
        bb.u[2] = 0u; bb.u[3] = 0u;
        accpv[c] =
            __builtin_amdgcn_mfma_f32_16x16x32_f16(ap.v, bb.v, accpv[c], 0, 0, 0);
      }
    }
  }
  if (w == 0) {
#pragma unroll
    for (int m = 16; m < 64; m <<= 1) {
      dh0 += __shfl_xor(dh0, m, 64); dh1 += __shfl_xor(dh1, m, 64);
      dh2 += __shfl_xor(dh2, m, 64); dh3 += __shfl_xor(dh3, m, 64);
    }
    if (lane < 16) {
      const int b = blockIdx.x / bpb;
      float* cb = Cbuf + (b * 16 + lane) * 4;
      atomicAdd(cb + 0, dh0); atomicAdd(cb + 1, dh1);
      atomicAdd(cb + 2, dh2); atomicAdd(cb + 3, dh3);
    }
  }
  // write T1 partials: dim = w*256 + col*16 + c, h = kg*4+reg
  float* po = part + ((size_t)blockIdx.x * 16) * 1024 + w * 256 + col * 16;
#pragma unroll
  for (int reg = 0; reg < 4; reg++) {
    const int h = kg * 4 + reg;
#pragma unroll
    for (int cg = 0; cg < 4; cg++) {
      float4 v;
      v.x = accpv[cg * 4 + 0][reg]; v.y = accpv[cg * 4 + 1][reg];
      v.z = accpv[cg * 4 + 2][reg]; v.w = accpv[cg * 4 + 3][reg];
      *(float4*)(po + (size_t)h * 1024 + cg * 4) = v;
    }
  }
}

// ---------- reduce partials + normalize + affine V-input assembly ----------
__global__ void k_reduce(const float* __restrict__ part, const float* __restrict__ Cbuf,
                         const float* __restrict__ g1, const float* __restrict__ b1,
                         const float* __restrict__ vg, const float* __restrict__ vb,
                         float* __restrict__ vpool, int bpb) {
  const int b = blockIdx.x >> 4, h = blockIdx.x & 15;
  const int t = threadIdx.x, d = t * 4;
  float4 a = make_float4(0.f, 0.f, 0.f, 0.f);
  for (int k = 0; k < bpb; k++) {
    const float4 p =
        *(const float4*)(part + ((size_t)((b * bpb + k) * 16 + h)) * 1024 + d);
    a.x += p.x; a.y += p.y; a.z += p.z; a.w += p.w;
  }
  const float4 C = ((const float4*)Cbuf)[b * 16 + h];  // den, C1, C2, C3 (unnorm)
  const float inv = 1.f / C.x;
  const float C1n = C.y * inv, C2n = C.z * inv, C3n = C.w * inv;
  const float4 gv = ((const float4*)g1)[t], bv = ((const float4*)b1)[t];
  const float4 vgv = ((const float4*)vg)[t], vbv = ((const float4*)vb)[t];
  float4 o;
  o.x = vgv.x * (gv.x * (a.x * inv - C2n) + bv.x * C1n - C3n) + vbv.x;
  o.y = vgv.y * (gv.y * (a.y * inv - C2n) + bv.y * C1n - C3n) + vbv.y;
  o.z = vgv.z * (gv.z * (a.z * inv - C2n) + bv.z * C1n - C3n) + vbv.z;
  o.w = vgv.w * (gv.w * (a.w * inv - C2n) + bv.w * C1n - C3n) + vbv.w;
  *(float4*)(vpool + ((size_t)b * H + h) * D + d) = o;
}

// ---------- out[b][j] = W[j,:] . src[b, head-sliced] + bias[j] ----------
__global__ void k_proj8(const float* __restrict__ src, const float* __restrict__ W,
                        const float* __restrict__ bias, float* __restrict__ out,
                        int bstride, int hstride) {
  const int j = blockIdx.x, lane = threadIdx.x;
  const int h = j >> 6;
  const float4* wr = (const float4*)(W + (size_t)j * D);
  float acc[8];
#pragma unroll
  for (int b = 0; b < 8; b++) acc[b] = 0.f;
#pragma unroll
  for (int k = 0; k < 4; k++) {
    const float4 w4 = wr[lane + 64 * k];
#pragma unroll
    for (int b = 0; b < 8; b++) {
      const float4 s4 =
          ((const float4*)(src + (size_t)b * bstride + (size_t)h * hstride))[lane + 64 * k];
      acc[b] = fmaf(w4.x, s4.x, acc[b]); acc[b] = fmaf(w4.y, s4.y, acc[b]);
      acc[b] = fmaf(w4.z, s4.z, acc[b]); acc[b] = fmaf(w4.w, s4.w, acc[b]);
    }
  }
#pragma unroll
  for (int b = 0; b < 8; b++) acc[b] = wred_sum(acc[b]);
  if (!lane) {
    const float bj = bias[j];
#pragma unroll
    for (int b = 0; b < 8; b++) out[(size_t)b * D + j] = acc[b] + bj;
  }
}

extern "C" void kernel_launch(void* const* d_in, const int* in_sizes, int n_in,
                              void* d_out, int out_size, void* d_ws, size_t ws_size,
                              hipStream_t stream) {
  const float* x = (const float*)d_in[0];
  const float* query = (const float*)d_in[1];
  const float* norm_g = (const float*)d_in[2];
  const float* norm_b = (const float*)d_in[3];
  const float* nq_g = (const float*)d_in[4];
  const float* nq_b = (const float*)d_in[5];
  const float* nk_g = (const float*)d_in[6];
  const float* nk_b = (const float*)d_in[7];
  const float* nv_g = (const float*)d_in[8];
  const float* nv_b = (const float*)d_in[9];
  const float* no_g = (const float*)d_in[10];
  const float* no_b = (const float*)d_in[11];
  const float* Wq = (const float*)d_in[12];
  const float* bq = (const float*)d_in[13];
  const float* Wk = (const float*)d_in[14];
  // d_in[15] = bk: constant per (b,h) in scores -> cancels in softmax
  const float* Wv = (const float*)d_in[16];
  const float* bv = (const float*)d_in[17];
  const float* Wo = (const float*)d_in[18];
  const float* bo = (const float*)d_in[19];

  char* ws = (char*)d_ws;
  float* qv = (float*)(ws + 0);           // 4 KB
  uint4* B1 = (uint4*)(ws + 4096);        // 32 KB
  uint4* gt = (uint4*)(ws + 36864);       // 2 KB
  uint4* g2t = (uint4*)(ws + 38912);      // 2 KB
  uint4* gbt = (uint4*)(ws + 40960);      // 2 KB
  float* hc = (float*)(ws + 43008);       // 256 B
  float* sconst = (float*)(ws + 43264);   // 64 B
  float* Cbuf = (float*)(ws + 43328);     // 2 KB
  float* vpool = (float*)(ws + 45568);    // 512 KB
  float* av = (float*)(ws + 569856);      // 32 KB
  float* yb = (float*)(ws + 602624);      // 32 KB
  float* part = (float*)(ws + 635904);    // NBLK*16*1024*4

  int NBLK = 512;
  if (635904ull + (size_t)NBLK * 16 * 1024 * 4 > ws_size) NBLK = 256;
  const int niter = NROWS / (16 * NBLK);
  const int bpb = NBLK / B;

  k_qln<<<256, 256, 0, stream>>>(query, nq_g, nq_b, Wq, bq, qv);
  k_prep0G<<<1, 256, 0, stream>>>(norm_g, norm_b, sconst, gt, g2t, gbt, hc, Cbuf);
  k_uprep64<<<64, 256, 0, stream>>>(qv, Wk, norm_g, norm_b, nk_g, nk_b, hc, B1);
  k_fused<<<NBLK, 256, 0, stream>>>(x, B1, gt, g2t, gbt, hc, sconst, part, Cbuf,
                                    niter, bpb);
  k_reduce<<<128, 256, 0, stream>>>(part, Cbuf, norm_g, norm_b, nv_g, nv_b, vpool, bpb);
  k_proj8<<<1024, 64, 0, stream>>>(vpool, Wv, bv, av, H * D, D);  // V-proj on pooled
  k_proj8<<<1024, 64, 0, stream>>>(av, Wo, bo, yb, D, 0);         // O-proj
  k_ln256<<<8, 256, 0, stream>>>(yb, no_g, no_b, (float*)d_out);
}

// Round 14
// 126.882 us; speedup vs baseline: 1.2819x; 1.2819x over previous
//
#include <hip/hip_runtime.h>
#include <math.h>

#define D 1024
#define S 8192
#define B 8
#define H 16
#define NROWS (B * S)
#define EPS_LN 1e-5f

typedef _Float16 h2 __attribute__((ext_vector_type(2)));
typedef __fp16 half8 __attribute__((ext_vector_type(8)));
typedef float f32x4 __attribute__((ext_vector_type(4)));

__device__ __forceinline__ float wred_sum(float v) {
#pragma unroll
  for (int m = 1; m < 64; m <<= 1) v += __shfl_xor(v, m, 64);
  return v;
}
__device__ __forceinline__ h2 pkh(float a, float b) {
#if __has_builtin(__builtin_amdgcn_cvt_pkrtz)
  return __builtin_bit_cast(h2, __builtin_amdgcn_cvt_pkrtz(a, b));
#else
  h2 r; r.x = (_Float16)a; r.y = (_Float16)b; return r;
#endif
}
__device__ __forceinline__ float fdot2(h2 a, h2 b, float c) {
#if __has_builtin(__builtin_amdgcn_fdot2)
  typedef __fp16 fp16v2 __attribute__((ext_vector_type(2)));
  return __builtin_amdgcn_fdot2(__builtin_bit_cast(fp16v2, a),
                                __builtin_bit_cast(fp16v2, b), c, false);
#else
  return c + (float)a.x * (float)b.x + (float)a.y * (float)b.y;
#endif
}
__device__ __forceinline__ h2 bch(unsigned int u) { return __builtin_bit_cast(h2, u); }
__device__ __forceinline__ unsigned int hbits(h2 v) {
  return __builtin_bit_cast(unsigned int, v);
}

// ---------- LN over one 1024-row per block (256 thr) ----------
__global__ void k_ln256(const float* __restrict__ in, const float* __restrict__ g,
                        const float* __restrict__ bb, float* __restrict__ out) {
  const int b = blockIdx.x, t = threadIdx.x;
  float4 v = ((const float4*)(in + (size_t)b * D))[t];
  float s = v.x + v.y + v.z + v.w;
  float s2 = fmaf(v.x, v.x, fmaf(v.y, v.y, fmaf(v.z, v.z, v.w * v.w)));
  __shared__ float red[8];
  float ws = wred_sum(s), ws2 = wred_sum(s2);
  const int lane = t & 63, wv = t >> 6;
  if (!lane) { red[wv] = ws; red[wv + 4] = ws2; }
  __syncthreads();
  ws = red[0] + red[1] + red[2] + red[3];
  ws2 = red[4] + red[5] + red[6] + red[7];
  const float m = ws * (1.f / D);
  const float rs = rsqrtf(ws2 * (1.f / D) - m * m + EPS_LN);
  const float4 gg = ((const float4*)g)[t], bv = ((const float4*)bb)[t];
  float4 o;
  o.x = (v.x - m) * rs * gg.x + bv.x;
  o.y = (v.y - m) * rs * gg.y + bv.y;
  o.z = (v.z - m) * rs * gg.z + bv.z;
  o.w = (v.w - m) * rs * gg.w + bv.w;
  ((float4*)(out + (size_t)b * D))[t] = o;
}

// ---------- fused: query LN (replicated) + q-projection ----------
__global__ void k_qln(const float* __restrict__ query, const float* __restrict__ ng,
                      const float* __restrict__ nb, const float* __restrict__ Wq,
                      const float* __restrict__ bq, float* __restrict__ qv) {
  __shared__ float qn[D];
  __shared__ float red[8];
  const int t = threadIdx.x, lane = t & 63, wv = t >> 6;
  float4 v = ((const float4*)query)[t];
  float s = v.x + v.y + v.z + v.w;
  float s2 = fmaf(v.x, v.x, fmaf(v.y, v.y, fmaf(v.z, v.z, v.w * v.w)));
  float ws = wred_sum(s), ws2 = wred_sum(s2);
  if (!lane) { red[wv] = ws; red[wv + 4] = ws2; }
  __syncthreads();
  ws = red[0] + red[1] + red[2] + red[3];
  ws2 = red[4] + red[5] + red[6] + red[7];
  const float m = ws * (1.f / D);
  const float rs = rsqrtf(ws2 * (1.f / D) - m * m + EPS_LN);
  const float4 gg = ((const float4*)ng)[t], bv = ((const float4*)nb)[t];
  float4 o;
  o.x = (v.x - m) * rs * gg.x + bv.x;
  o.y = (v.y - m) * rs * gg.y + bv.y;
  o.z = (v.z - m) * rs * gg.z + bv.z;
  o.w = (v.w - m) * rs * gg.w + bv.w;
  ((float4*)qn)[t] = o;
  __syncthreads();
  const int j = blockIdx.x * 4 + wv;
  const float4* wr = (const float4*)(Wq + (size_t)j * D);
  float acc = 0.f;
#pragma unroll
  for (int k = 0; k < 4; k++) {
    float4 a = ((const float4*)qn)[lane + 64 * k], w = wr[lane + 64 * k];
    acc = fmaf(a.x, w.x, acc); acc = fmaf(a.y, w.y, acc);
    acc = fmaf(a.z, w.z, acc); acc = fmaf(a.w, w.w, acc);
  }
  acc = wred_sum(acc);
  if (!lane) qv[j] = acc + bq[j];
}

// ---------- fused: weight scalars + g-tables + zero hc/Cbuf ----------
__global__ void k_prep0G(const float* __restrict__ g, const float* __restrict__ b,
                         float* __restrict__ sconst, uint4* __restrict__ gt,
                         uint4* __restrict__ g2t, uint4* __restrict__ gbt,
                         float* __restrict__ hc, float* __restrict__ Cbuf) {
  const int t = threadIdx.x;
  float4 gv = ((const float4*)g)[t], bv = ((const float4*)b)[t];
  float sg = gv.x + gv.y + gv.z + gv.w;
  float sb = bv.x + bv.y + bv.z + bv.w;
  float sbb = bv.x * bv.x + bv.y * bv.y + bv.z * bv.z + bv.w * bv.w;
  float sgb = gv.x * bv.x + gv.y * bv.y + gv.z * bv.z + gv.w * bv.w;
  float sgg = gv.x * gv.x + gv.y * gv.y + gv.z * gv.z + gv.w * gv.w;
  __shared__ float red[4][5];
  sg = wred_sum(sg); sb = wred_sum(sb); sbb = wred_sum(sbb);
  sgb = wred_sum(sgb); sgg = wred_sum(sgg);
  const int lane = t & 63, wv = t >> 6;
  if (!lane) { red[wv][0] = sg; red[wv][1] = sb; red[wv][2] = sbb; red[wv][3] = sgb; red[wv][4] = sgg; }
  __syncthreads();
  if (t < 5) sconst[t] = red[0][t] + red[1][t] + red[2][t] + red[3][t];
  if (t < 16) ((float4*)hc)[t] = make_float4(0.f, 0.f, 0.f, 0.f);
  if (t < 128) ((float4*)Cbuf)[t] = make_float4(0.f, 0.f, 0.f, 0.f);
  if (t < 128) {
    const int grp = t;
    const int k0 = (grp >> 2) * 32 + (grp & 3) * 8;
    unsigned int a[4], bb2[4], c[4];
#pragma unroll
    for (int p = 0; p < 4; p++) {
      const int k = k0 + 2 * p;
      const float g0 = g[k], g1v = g[k + 1];
      const float b0 = b[k], b1v = b[k + 1];
      a[p] = hbits(pkh(g0, g1v));
      bb2[p] = hbits(pkh(g0 * g0, g1v * g1v));
      c[p] = hbits(pkh(g0 * b0, g1v * b1v));
    }
    gt[grp] = make_uint4(a[0], a[1], a[2], a[3]);
    g2t[grp] = make_uint4(bb2[0], bb2[1], bb2[2], bb2[3]);
    gbt[grp] = make_uint4(c[0], c[1], c[2], c[3]);
  }
}

// ---------- per (head, quarter): U-proj slice + hc partials (atomic) + B1 frags ----
__global__ void k_uprep64(const float* __restrict__ qv, const float* __restrict__ Wk,
                          const float* __restrict__ g1, const float* __restrict__ b1,
                          const float* __restrict__ kgw, const float* __restrict__ kbw,
                          float* __restrict__ hc, uint4* __restrict__ B1) {
  __shared__ float sUf[256];
  __shared__ float qh[64];
  __shared__ float red[4][4];
  const int h = blockIdx.x >> 2, q = blockIdx.x & 3, t = threadIdx.x;
  if (t < 64) qh[t] = qv[h * 64 + t];
  __syncthreads();
  const int d = q * 256 + t;
  float acc = 0.f;
#pragma unroll 4
  for (int e = 0; e < 64; e++)
    acc = fmaf(qh[e], Wk[(size_t)(h * 64 + e) * D + d], acc);
  acc *= 0.125f;  // 1/sqrt(64)
  sUf[t] = acc;
  const float gv = g1[d], bv = b1[d], kgv = kgw[d], kbv = kbw[d];
  float p2 = acc * kgv * bv;
  float p3 = acc * gv * kgv;
  float p4 = acc * kgv;
  float p5 = acc * kbv;
  p2 = wred_sum(p2); p3 = wred_sum(p3); p4 = wred_sum(p4); p5 = wred_sum(p5);
  const int lane = t & 63, wv = t >> 6;
  if (!lane) { red[wv][0] = p2; red[wv][1] = p3; red[wv][2] = p4; red[wv][3] = p5; }
  __syncthreads();
  if (t < 4)
    atomicAdd(&hc[t * 16 + h], red[0][t] + red[1][t] + red[2][t] + red[3][t]);
  if (t < 32) {
    const int grp = q * 32 + t;
    const int k0 = (grp >> 2) * 32 + (grp & 3) * 8;  // global dim base
    const int kl = k0 - q * 256;                      // local 0..255
    unsigned int wv2[4];
#pragma unroll
    for (int p = 0; p < 4; p++) {
      const int k = kl + 2 * p, kg2 = k0 + 2 * p;
      const float e0 = sUf[k] * g1[kg2] * kgw[kg2];
      const float e1 = sUf[k + 1] * g1[kg2 + 1] * kgw[kg2 + 1];
      wv2[p] = hbits(pkh(e0, e1));
    }
    B1[grp * 16 + h] = make_uint4(wv2[0], wv2[1], wv2[2], wv2[3]);
  }
}

// ---------- SINGLE PASS over x: scores (MFMA) + stats + online exp + PV (MFMA) ----
// B1 fragments hoisted to registers (iteration-invariant per lane); LDS 51 KB ->
// 3 blocks/CU; double-buffered exchange -> 1 barrier/iter; PV from per-wave xl tile.
__global__ __launch_bounds__(256) void k_fused(
    const float* __restrict__ x, const uint4* __restrict__ B1,
    const uint4* __restrict__ gt, const uint4* __restrict__ g2t,
    const uint4* __restrict__ gbt, const float* __restrict__ hc,
    const float* __restrict__ sconst, float* __restrict__ part,
    float* __restrict__ Cbuf, int niter, int bpb) {
  __shared__ __align__(16) uint4 sg[128], sg2[128], sgb[128];  // 6 KB
  __shared__ __align__(16) unsigned int xl[4][16 * 133];       // 34 KB (x f16 tiles)
  __shared__ __align__(16) f32x4 sred[2][4][64];               // 8 KB
  __shared__ float stat[2][4][16][6];                          // 3 KB
  if (threadIdx.x < 128) {
    sg[threadIdx.x] = gt[threadIdx.x];
    sg2[threadIdx.x] = g2t[threadIdx.x];
    sgb[threadIdx.x] = gbt[threadIdx.x];
  }
  const int lane = threadIdx.x & 63, w = threadIdx.x >> 6;
  const int col = lane & 15, kg = lane >> 4;
  // iteration-invariant B fragments -> registers (8 x uint4)
  uint4 rB[8];
#pragma unroll
  for (int ks = 0; ks < 8; ks++) rB[ks] = B1[((w * 8 + ks) * 4 + kg) * 16 + col];
  __syncthreads();
  const float c2 = hc[col], c3 = hc[16 + col], c4 = hc[32 + col], c5 = hc[48 + col];
  const float Sg1 = sconst[0], Sb1 = sconst[1], Sbbc = sconst[2];
  const float Sgbc = sconst[3], Sggc = sconst[4];
  const h2 one = {(_Float16)1.f, (_Float16)1.f};
  const int sh = (col & 1) * 16;
  f32x4 accpv[16];
#pragma unroll
  for (int c = 0; c < 16; c++) accpv[c] = (f32x4){0.f, 0.f, 0.f, 0.f};
  float dh0 = 0.f, dh1 = 0.f, dh2 = 0.f, dh3 = 0.f;
  const int rbase = blockIdx.x * (16 * niter);
#pragma unroll 1
  for (int it = 0; it < niter; it++) {
    const int p = it & 1;
    const int r0 = rbase + it * 16;
    const float* xrow = x + (size_t)(r0 + col) * D + w * 256 + kg * 8;
    f32x4 sacc = {0.f, 0.f, 0.f, 0.f};
    float S0 = 0, S1 = 0, Sa = 0, Sb = 0, Sc = 0, Sd = 0;
#pragma unroll
    for (int ks = 0; ks < 8; ks++) {
      const float4 A0 = *(const float4*)(xrow + ks * 32);
      const float4 A1 = *(const float4*)(xrow + ks * 32 + 4);
      const h2 a0 = pkh(A0.x, A0.y), a1 = pkh(A0.z, A0.w);
      const h2 a2 = pkh(A1.x, A1.y), a3 = pkh(A1.z, A1.w);
      const int gidx = (w * 8 + ks) * 4 + kg;
      const uint4 gu = sg[gidx], g2u = sg2[gidx], gbu = sgb[gidx];
      S0 = fdot2(a0, one, S0); S0 = fdot2(a1, one, S0);
      S0 = fdot2(a2, one, S0); S0 = fdot2(a3, one, S0);
      S1 = fdot2(a0, a0, S1); S1 = fdot2(a1, a1, S1);
      S1 = fdot2(a2, a2, S1); S1 = fdot2(a3, a3, S1);
      const h2 g0 = bch(gu.x), g1p = bch(gu.y), g2p = bch(gu.z), g3p = bch(gu.w);
      Sa = fdot2(g0, a0, Sa); Sa = fdot2(g1p, a1, Sa);
      Sa = fdot2(g2p, a2, Sa); Sa = fdot2(g3p, a3, Sa);
      const h2 G0 = bch(g2u.x), G1 = bch(g2u.y), G2 = bch(g2u.z), G3 = bch(g2u.w);
      Sb = fdot2(G0, a0, Sb); Sb = fdot2(G1, a1, Sb);
      Sb = fdot2(G2, a2, Sb); Sb = fdot2(G3, a3, Sb);
      Sc = fdot2(G0, a0 * a0, Sc); Sc = fdot2(G1, a1 * a1, Sc);
      Sc = fdot2(G2, a2 * a2, Sc); Sc = fdot2(G3, a3 * a3, Sc);
      const h2 Q0 = bch(gbu.x), Q1 = bch(gbu.y), Q2 = bch(gbu.z), Q3 = bch(gbu.w);
      Sd = fdot2(Q0, a0, Sd); Sd = fdot2(Q1, a1, Sd);
      Sd = fdot2(Q2, a2, Sd); Sd = fdot2(Q3, a3, Sd);
      union { h2 pp[4]; half8 v; } ua;
      ua.pp[0] = a0; ua.pp[1] = a1; ua.pp[2] = a2; ua.pp[3] = a3;
      sacc = __builtin_amdgcn_mfma_f32_16x16x32_f16(
          ua.v, __builtin_bit_cast(half8, rB[ks]), sacc, 0, 0, 0);
      uint4 xw;
      xw.x = hbits(a0); xw.y = hbits(a1); xw.z = hbits(a2); xw.w = hbits(a3);
      *(uint4*)&xl[w][col * 133 + kg * 4 + ks * 16] = xw;
    }
#pragma unroll
    for (int m = 16; m < 64; m <<= 1) {
      S0 += __shfl_xor(S0, m, 64); S1 += __shfl_xor(S1, m, 64);
      Sa += __shfl_xor(Sa, m, 64); Sb += __shfl_xor(Sb, m, 64);
      Sc += __shfl_xor(Sc, m, 64); Sd += __shfl_xor(Sd, m, 64);
    }
    if (lane < 16) {
      stat[p][w][lane][0] = S0; stat[p][w][lane][1] = S1; stat[p][w][lane][2] = Sa;
      stat[p][w][lane][3] = Sb; stat[p][w][lane][4] = Sc; stat[p][w][lane][5] = Sd;
    }
    sred[p][w][lane] = sacc;
    __syncthreads();  // single barrier per iteration (double-buffered exchange)
    f32x4 full = sred[p][0][lane];
    full += sred[p][1][lane]; full += sred[p][2][lane]; full += sred[p][3][lane];
    float T0 = 0, T1v = 0, Ta = 0, Tb = 0, Tc = 0, Td = 0;
#pragma unroll
    for (int ww = 0; ww < 4; ww++) {
      T0 += stat[p][ww][col][0]; T1v += stat[p][ww][col][1]; Ta += stat[p][ww][col][2];
      Tb += stat[p][ww][col][3]; Tc += stat[p][ww][col][4]; Td += stat[p][ww][col][5];
    }
    const float m1 = T0 * (1.f / D);
    const float rs1 = rsqrtf(T1v * (1.f / D) - m1 * m1 + EPS_LN);
    const float m2 = (rs1 * (Ta - m1 * Sg1) + Sb1) * (1.f / D);
    const float sxn2 = rs1 * rs1 * Tc + 2.f * rs1 * (Td - m1 * rs1 * Tb) +
                       (Sbbc - 2.f * m1 * rs1 * Sgbc + m1 * m1 * rs1 * rs1 * Sggc);
    const float rs2 = rsqrtf(sxn2 * (1.f / D) - m2 * m2 + EPS_LN);
    const float v1 = rs1 * rs2, v2 = v1 * m1, v3 = rs2, v4 = rs2 * m2;
    float ap_[4];
#pragma unroll
    for (int j = 0; j < 4; j++) {
      const int rj = kg * 4 + j;
      const float w1 = __shfl(v1, rj, 64), w2 = __shfl(v2, rj, 64);
      const float w3 = __shfl(v3, rj, 64), w4 = __shfl(v4, rj, 64);
      const float s = w1 * full[j] - w2 * c3 + w3 * c2 - w4 * c4 + c5;
      const float e = __expf(s);
      ap_[j] = e * w1;
      if (w == 0) { dh0 += e; dh1 += e * w3; dh2 += e * w2; dh3 += e * w4; }
    }
    union { h2 pp[4]; half8 v; } ap;
    ap.pp[0] = pkh(ap_[0], ap_[1]); ap.pp[1] = pkh(ap_[2], ap_[3]);
    ap.pp[2] = bch(0u); ap.pp[3] = bch(0u);
    const unsigned int* xw = xl[w];
#pragma unroll
    for (int c = 0; c < 16; c++) {
      const int bidx = c * 8 + (col >> 1);
      const unsigned int r0w = xw[(kg * 4 + 0) * 133 + bidx];
      const unsigned int r1w = xw[(kg * 4 + 1) * 133 + bidx];
      const unsigned int r2w = xw[(kg * 4 + 2) * 133 + bidx];
      const unsigned int r3w = xw[(kg * 4 + 3) * 133 + bidx];
      union { unsigned int u[4]; half8 v; } bb;
      bb.u[0] = ((r0w >> sh) & 0xffffu) | (((r1w >> sh) & 0xffffu) << 16);
      bb.u[1] = ((r2w >> sh) & 0xffffu) | (((r3w >> sh) & 0xffffu) << 16);
      bb.u[2] = 0u; bb.u[3] = 0u;
      accpv[c] = __builtin_amdgcn_mfma_f32_16x16x32_f16(ap.v, bb.v, accpv[c], 0, 0, 0);
    }
  }
  if (w == 0) {
#pragma unroll
    for (int m = 16; m < 64; m <<= 1) {
      dh0 += __shfl_xor(dh0, m, 64); dh1 += __shfl_xor(dh1, m, 64);
      dh2 += __shfl_xor(dh2, m, 64); dh3 += __shfl_xor(dh3, m, 64);
    }
    if (lane < 16) {
      const int b = blockIdx.x / bpb;
      float* cb = Cbuf + (b * 16 + lane) * 4;
      atomicAdd(cb + 0, dh0); atomicAdd(cb + 1, dh1);
      atomicAdd(cb + 2, dh2); atomicAdd(cb + 3, dh3);
    }
  }
  float* po = part + ((size_t)blockIdx.x * 16) * 1024 + w * 256;
#pragma unroll
  for (int c = 0; c < 16; c++) {
#pragma unroll
    for (int reg = 0; reg < 4; reg++) {
      const int h = kg * 4 + reg;
      po[(size_t)h * 1024 + c * 16 + col] = accpv[c][reg];
    }
  }
}

// ---------- reduce partials + normalize + affine V-input assembly ----------
__global__ void k_reduce(const float* __restrict__ part, const float* __restrict__ Cbuf,
                         const float* __restrict__ g1, const float* __restrict__ b1,
                         const float* __restrict__ vg, const float* __restrict__ vb,
                         float* __restrict__ vpool, int bpb) {
  const int b = blockIdx.x >> 4, h = blockIdx.x & 15;
  const int t = threadIdx.x, d = t * 4;
  float4 a = make_float4(0.f, 0.f, 0.f, 0.f);
  for (int k = 0; k < bpb; k++) {
    const float4 p =
        *(const float4*)(part + ((size_t)((b * bpb + k) * 16 + h)) * 1024 + d);
    a.x += p.x; a.y += p.y; a.z += p.z; a.w += p.w;
  }
  const float4 C = ((const float4*)Cbuf)[b * 16 + h];  // den, C1, C2, C3 (unnorm)
  const float inv = 1.f / C.x;
  const float C1n = C.y * inv, C2n = C.z * inv, C3n = C.w * inv;
  const float4 gv = ((const float4*)g1)[t], bv = ((const float4*)b1)[t];
  const float4 vgv = ((const float4*)vg)[t], vbv = ((const float4*)vb)[t];
  float4 o;
  o.x = vgv.x * (gv.x * (a.x * inv - C2n) + bv.x * C1n - C3n) + vbv.x;
  o.y = vgv.y * (gv.y * (a.y * inv - C2n) + bv.y * C1n - C3n) + vbv.y;
  o.z = vgv.z * (gv.z * (a.z * inv - C2n) + bv.z * C1n - C3n) + vbv.z;
  o.w = vgv.w * (gv.w * (a.w * inv - C2n) + bv.w * C1n - C3n) + vbv.w;
  *(float4*)(vpool + ((size_t)b * H + h) * D + d) = o;
}

// ---------- out[b][j] = W[j,:] . src[b, head-sliced] + bias[j] ----------
__global__ void k_proj8(const float* __restrict__ src, const float* __restrict__ W,
                        const float* __restrict__ bias, float* __restrict__ out,
                        int bstride, int hstride) {
  const int j = blockIdx.x, lane = threadIdx.x;
  const int h = j >> 6;
  const float4* wr = (const float4*)(W + (size_t)j * D);
  float acc[8];
#pragma unroll
  for (int b = 0; b < 8; b++) acc[b] = 0.f;
#pragma unroll
  for (int k = 0; k < 4; k++) {
    const float4 w4 = wr[lane + 64 * k];
#pragma unroll
    for (int b = 0; b < 8; b++) {
      const float4 s4 =
          ((const float4*)(src + (size_t)b * bstride + (size_t)h * hstride))[lane + 64 * k];
      acc[b] = fmaf(w4.x, s4.x, acc[b]); acc[b] = fmaf(w4.y, s4.y, acc[b]);
      acc[b] = fmaf(w4.z, s4.z, acc[b]); acc[b] = fmaf(w4.w, s4.w, acc[b]);
    }
  }
#pragma unroll
  for (int b = 0; b < 8; b++) acc[b] = wred_sum(acc[b]);
  if (!lane) {
    const float bj = bias[j];
#pragma unroll
    for (int b = 0; b < 8; b++) out[(size_t)b * D + j] = acc[b] + bj;
  }
}

extern "C" void kernel_launch(void* const* d_in, const int* in_sizes, int n_in,
                              void* d_out, int out_size, void* d_ws, size_t ws_size,
                              hipStream_t stream) {
  const float* x = (const float*)d_in[0];
  const float* query = (const float*)d_in[1];
  const float* norm_g = (const float*)d_in[2];
  const float* norm_b = (const float*)d_in[3];
  const float* nq_g = (const float*)d_in[4];
  const float* nq_b = (const float*)d_in[5];
  const float* nk_g = (const float*)d_in[6];
  const float* nk_b = (const float*)d_in[7];
  const float* nv_g = (const float*)d_in[8];
  const float* nv_b = (const float*)d_in[9];
  const float* no_g = (const float*)d_in[10];
  const float* no_b = (const float*)d_in[11];
  const float* Wq = (const float*)d_in[12];
  const float* bq = (const float*)d_in[13];
  const float* Wk = (const float*)d_in[14];
  // d_in[15] = bk: constant per (b,h) in scores -> cancels in softmax
  const float* Wv = (const float*)d_in[16];
  const float* bv = (const float*)d_in[17];
  const float* Wo = (const float*)d_in[18];
  const float* bo = (const float*)d_in[19];

  char* ws = (char*)d_ws;
  float* qv = (float*)(ws + 0);           // 4 KB
  uint4* B1 = (uint4*)(ws + 4096);        // 32 KB
  uint4* gt = (uint4*)(ws + 36864);       // 2 KB
  uint4* g2t = (uint4*)(ws + 38912);      // 2 KB
  uint4* gbt = (uint4*)(ws + 40960);      // 2 KB
  float* hc = (float*)(ws + 43008);       // 256 B
  float* sconst = (float*)(ws + 43264);   // 64 B
  float* Cbuf = (float*)(ws + 43328);     // 2 KB
  float* vpool = (float*)(ws + 45568);    // 512 KB
  float* av = (float*)(ws + 569856);      // 32 KB
  float* yb = (float*)(ws + 602624);      // 32 KB
  float* part = (float*)(ws + 635904);    // NBLK*16*1024*4

  int NBLK = 512;
  if (635904ull + (size_t)NBLK * 16 * 1024 * 4 > ws_size) NBLK = 256;
  const int niter = NROWS / (16 * NBLK);
  const int bpb = NBLK / B;

  k_qln<<<256, 256, 0, stream>>>(query, nq_g, nq_b, Wq, bq, qv);
  k_prep0G<<<1, 256, 0, stream>>>(norm_g, norm_b, sconst, gt, g2t, gbt, hc, Cbuf);
  k_uprep64<<<64, 256, 0, stream>>>(qv, Wk, norm_g, norm_b, nk_g, nk_b, hc, B1);
  k_fused<<<NBLK, 256, 0, stream>>>(x, B1, gt, g2t, gbt, hc, sconst, part, Cbuf,
                                    niter, bpb);
  k_reduce<<<128, 256, 0, stream>>>(part, Cbuf, norm_g, norm_b, nv_g, nv_b, vpool, bpb);
  k_proj8<<<1024, 64, 0, stream>>>(vpool, Wv, bv, av, H * D, D);  // V-proj on pooled
  k_proj8<<<1024, 64, 0, stream>>>(av, Wo, bo, yb, D, 0);         // O-proj
  k_ln256<<<8, 256, 0, stream>>>(yb, no_g, no_b, (float*)d_out);
}

// Round 15
// 114.514 us; speedup vs baseline: 1.4204x; 1.1080x over previous
//
#include <hip/hip_runtime.h>
#include <math.h>

#define D 1024
#define S 8192
#define B 8
#define H 16
#define NROWS (B * S)
#define EPS_LN 1e-5f

typedef _Float16 h2 __attribute__((ext_vector_type(2)));
typedef __fp16 half8 __attribute__((ext_vector_type(8)));
typedef float f32x4 __attribute__((ext_vector_type(4)));

__device__ __forceinline__ float wred_sum(float v) {
#pragma unroll
  for (int m = 1; m < 64; m <<= 1) v += __shfl_xor(v, m, 64);
  return v;
}
__device__ __forceinline__ h2 pkh(float a, float b) {
#if __has_builtin(__builtin_amdgcn_cvt_pkrtz)
  return __builtin_bit_cast(h2, __builtin_amdgcn_cvt_pkrtz(a, b));
#else
  h2 r; r.x = (_Float16)a; r.y = (_Float16)b; return r;
#endif
}
__device__ __forceinline__ float fdot2(h2 a, h2 b, float c) {
#if __has_builtin(__builtin_amdgcn_fdot2)
  typedef __fp16 fp16v2 __attribute__((ext_vector_type(2)));
  return __builtin_amdgcn_fdot2(__builtin_bit_cast(fp16v2, a),
                                __builtin_bit_cast(fp16v2, b), c, false);
#else
  return c + (float)a.x * (float)b.x + (float)a.y * (float)b.y;
#endif
}
__device__ __forceinline__ h2 bch(unsigned int u) { return __builtin_bit_cast(h2, u); }
__device__ __forceinline__ unsigned int hbits(h2 v) {
  return __builtin_bit_cast(unsigned int, v);
}

// ---------- LN over one 1024-row per block (256 thr) ----------
__global__ void k_ln256(const float* __restrict__ in, const float* __restrict__ g,
                        const float* __restrict__ bb, float* __restrict__ out) {
  const int b = blockIdx.x, t = threadIdx.x;
  float4 v = ((const float4*)(in + (size_t)b * D))[t];
  float s = v.x + v.y + v.z + v.w;
  float s2 = fmaf(v.x, v.x, fmaf(v.y, v.y, fmaf(v.z, v.z, v.w * v.w)));
  __shared__ float red[8];
  float ws = wred_sum(s), ws2 = wred_sum(s2);
  const int lane = t & 63, wv = t >> 6;
  if (!lane) { red[wv] = ws; red[wv + 4] = ws2; }
  __syncthreads();
  ws = red[0] + red[1] + red[2] + red[3];
  ws2 = red[4] + red[5] + red[6] + red[7];
  const float m = ws * (1.f / D);
  const float rs = rsqrtf(ws2 * (1.f / D) - m * m + EPS_LN);
  const float4 gg = ((const float4*)g)[t], bv = ((const float4*)bb)[t];
  float4 o;
  o.x = (v.x - m) * rs * gg.x + bv.x;
  o.y = (v.y - m) * rs * gg.y + bv.y;
  o.z = (v.z - m) * rs * gg.z + bv.z;
  o.w = (v.w - m) * rs * gg.w + bv.w;
  ((float4*)(out + (size_t)b * D))[t] = o;
}

// ---------- fused: query LN (replicated) + q-projection ----------
__global__ void k_qln(const float* __restrict__ query, const float* __restrict__ ng,
                      const float* __restrict__ nb, const float* __restrict__ Wq,
                      const float* __restrict__ bq, float* __restrict__ qv) {
  __shared__ float qn[D];
  __shared__ float red[8];
  const int t = threadIdx.x, lane = t & 63, wv = t >> 6;
  float4 v = ((const float4*)query)[t];
  float s = v.x + v.y + v.z + v.w;
  float s2 = fmaf(v.x, v.x, fmaf(v.y, v.y, fmaf(v.z, v.z, v.w * v.w)));
  float ws = wred_sum(s), ws2 = wred_sum(s2);
  if (!lane) { red[wv] = ws; red[wv + 4] = ws2; }
  __syncthreads();
  ws = red[0] + red[1] + red[2] + red[3];
  ws2 = red[4] + red[5] + red[6] + red[7];
  const float m = ws * (1.f / D);
  const float rs = rsqrtf(ws2 * (1.f / D) - m * m + EPS_LN);
  const float4 gg = ((const float4*)ng)[t], bv = ((const float4*)nb)[t];
  float4 o;
  o.x = (v.x - m) * rs * gg.x + bv.x;
  o.y = (v.y - m) * rs * gg.y + bv.y;
  o.z = (v.z - m) * rs * gg.z + bv.z;
  o.w = (v.w - m) * rs * gg.w + bv.w;
  ((float4*)qn)[t] = o;
  __syncthreads();
  const int j = blockIdx.x * 4 + wv;
  const float4* wr = (const float4*)(Wq + (size_t)j * D);
  float acc = 0.f;
#pragma unroll
  for (int k = 0; k < 4; k++) {
    float4 a = ((const float4*)qn)[lane + 64 * k], w = wr[lane + 64 * k];
    acc = fmaf(a.x, w.x, acc); acc = fmaf(a.y, w.y, acc);
    acc = fmaf(a.z, w.z, acc); acc = fmaf(a.w, w.w, acc);
  }
  acc = wred_sum(acc);
  if (!lane) qv[j] = acc + bq[j];
}

// ---------- fused: weight scalars + g-tables + zero hc/Cbuf ----------
__global__ void k_prep0G(const float* __restrict__ g, const float* __restrict__ b,
                         float* __restrict__ sconst, uint4* __restrict__ gt,
                         uint4* __restrict__ g2t, uint4* __restrict__ gbt,
                         float* __restrict__ hc, float* __restrict__ Cbuf) {
  const int t = threadIdx.x;
  float4 gv = ((const float4*)g)[t], bv = ((const float4*)b)[t];
  float sg = gv.x + gv.y + gv.z + gv.w;
  float sb = bv.x + bv.y + bv.z + bv.w;
  float sbb = bv.x * bv.x + bv.y * bv.y + bv.z * bv.z + bv.w * bv.w;
  float sgb = gv.x * bv.x + gv.y * bv.y + gv.z * bv.z + gv.w * bv.w;
  float sgg = gv.x * gv.x + gv.y * gv.y + gv.z * gv.z + gv.w * gv.w;
  __shared__ float red[4][5];
  sg = wred_sum(sg); sb = wred_sum(sb); sbb = wred_sum(sbb);
  sgb = wred_sum(sgb); sgg = wred_sum(sgg);
  const int lane = t & 63, wv = t >> 6;
  if (!lane) { red[wv][0] = sg; red[wv][1] = sb; red[wv][2] = sbb; red[wv][3] = sgb; red[wv][4] = sgg; }
  __syncthreads();
  if (t < 5) sconst[t] = red[0][t] + red[1][t] + red[2][t] + red[3][t];
  if (t < 16) ((float4*)hc)[t] = make_float4(0.f, 0.f, 0.f, 0.f);
  if (t < 128) ((float4*)Cbuf)[t] = make_float4(0.f, 0.f, 0.f, 0.f);
  if (t < 128) {
    const int grp = t;
    const int k0 = (grp >> 2) * 32 + (grp & 3) * 8;
    unsigned int a[4], bb2[4], c[4];
#pragma unroll
    for (int p = 0; p < 4; p++) {
      const int k = k0 + 2 * p;
      const float g0 = g[k], g1v = g[k + 1];
      const float b0 = b[k], b1v = b[k + 1];
      a[p] = hbits(pkh(g0, g1v));
      bb2[p] = hbits(pkh(g0 * g0, g1v * g1v));
      c[p] = hbits(pkh(g0 * b0, g1v * b1v));
    }
    gt[grp] = make_uint4(a[0], a[1], a[2], a[3]);
    g2t[grp] = make_uint4(bb2[0], bb2[1], bb2[2], bb2[3]);
    gbt[grp] = make_uint4(c[0], c[1], c[2], c[3]);
  }
}

// ---------- per (head, quarter): U-proj slice + hc partials (atomic) + B1 frags ----
__global__ void k_uprep64(const float* __restrict__ qv, const float* __restrict__ Wk,
                          const float* __restrict__ g1, const float* __restrict__ b1,
                          const float* __restrict__ kgw, const float* __restrict__ kbw,
                          float* __restrict__ hc, uint4* __restrict__ B1) {
  __shared__ float sUf[256];
  __shared__ float qh[64];
  __shared__ float red[4][4];
  const int h = blockIdx.x >> 2, q = blockIdx.x & 3, t = threadIdx.x;
  if (t < 64) qh[t] = qv[h * 64 + t];
  __syncthreads();
  const int d = q * 256 + t;
  float acc = 0.f;
#pragma unroll 4
  for (int e = 0; e < 64; e++)
    acc = fmaf(qh[e], Wk[(size_t)(h * 64 + e) * D + d], acc);
  acc *= 0.125f;  // 1/sqrt(64)
  sUf[t] = acc;
  const float gv = g1[d], bv = b1[d], kgv = kgw[d], kbv = kbw[d];
  float p2 = acc * kgv * bv;
  float p3 = acc * gv * kgv;
  float p4 = acc * kgv;
  float p5 = acc * kbv;
  p2 = wred_sum(p2); p3 = wred_sum(p3); p4 = wred_sum(p4); p5 = wred_sum(p5);
  const int lane = t & 63, wv = t >> 6;
  if (!lane) { red[wv][0] = p2; red[wv][1] = p3; red[wv][2] = p4; red[wv][3] = p5; }
  __syncthreads();
  if (t < 4)
    atomicAdd(&hc[t * 16 + h], red[0][t] + red[1][t] + red[2][t] + red[3][t]);
  if (t < 32) {
    const int grp = q * 32 + t;
    const int k0 = (grp >> 2) * 32 + (grp & 3) * 8;  // global dim base
    const int kl = k0 - q * 256;                      // local 0..255
    unsigned int wv2[4];
#pragma unroll
    for (int p = 0; p < 4; p++) {
      const int k = kl + 2 * p, kg2 = k0 + 2 * p;
      const float e0 = sUf[k] * g1[kg2] * kgw[kg2];
      const float e1 = sUf[k + 1] * g1[kg2 + 1] * kgw[kg2 + 1];
      wv2[p] = hbits(pkh(e0, e1));
    }
    B1[grp * 16 + h] = make_uint4(wv2[0], wv2[1], wv2[2], wv2[3]);
  }
}

// ---------- SINGLE PASS over x: scores (MFMA) + stats + online exp + PV (MFMA) ----
__global__ __launch_bounds__(256) void k_fused(
    const float* __restrict__ x, const uint4* __restrict__ B1,
    const uint4* __restrict__ gt, const uint4* __restrict__ g2t,
    const uint4* __restrict__ gbt, const float* __restrict__ hc,
    const float* __restrict__ sconst, float* __restrict__ part,
    float* __restrict__ Cbuf, int niter, int bpb) {
  __shared__ __align__(16) uint4 sB[2048];                     // 32 KB
  __shared__ __align__(16) uint4 sg[128], sg2[128], sgb[128];  // 6 KB
  __shared__ __align__(16) unsigned int xl[4][16 * 133];       // 34 KB (x f16 tiles)
  __shared__ __align__(16) f32x4 sred[4][64];                  // 4 KB
  __shared__ float stat[4][16][6];                             // 1.5 KB
  for (int i = threadIdx.x; i < 2048; i += 256) sB[i] = B1[i];
  if (threadIdx.x < 128) {
    sg[threadIdx.x] = gt[threadIdx.x];
    sg2[threadIdx.x] = g2t[threadIdx.x];
    sgb[threadIdx.x] = gbt[threadIdx.x];
  }
  __syncthreads();
  const int lane = threadIdx.x & 63, w = threadIdx.x >> 6;
  const int col = lane & 15, kg = lane >> 4;
  const float c2 = hc[col], c3 = hc[16 + col], c4 = hc[32 + col], c5 = hc[48 + col];
  const float Sg1 = sconst[0], Sb1 = sconst[1], Sbbc = sconst[2];
  const float Sgbc = sconst[3], Sggc = sconst[4];
  const h2 one = {(_Float16)1.f, (_Float16)1.f};
  const int sh = (col & 1) * 16;
  f32x4 accpv[16];
#pragma unroll
  for (int c = 0; c < 16; c++) accpv[c] = (f32x4){0.f, 0.f, 0.f, 0.f};
  float dh0 = 0.f, dh1 = 0.f, dh2 = 0.f, dh3 = 0.f;
  const int rbase = blockIdx.x * (16 * niter);
#pragma unroll 1
  for (int it = 0; it < niter; it++) {
    const int r0 = rbase + it * 16;
    const float* xrow = x + (size_t)(r0 + col) * D + w * 256 + kg * 8;
    f32x4 sacc = {0.f, 0.f, 0.f, 0.f};
    float S0 = 0, S1 = 0, Sa = 0, Sb = 0, Sc = 0, Sd = 0;
#pragma unroll
    for (int ks = 0; ks < 8; ks++) {
      const float4 A0 = *(const float4*)(xrow + ks * 32);
      const float4 A1 = *(const float4*)(xrow + ks * 32 + 4);
      const h2 a0 = pkh(A0.x, A0.y), a1 = pkh(A0.z, A0.w);
      const h2 a2 = pkh(A1.x, A1.y), a3 = pkh(A1.z, A1.w);
      const int gidx = (w * 8 + ks) * 4 + kg;
      const uint4 bu = sB[gidx * 16 + col];
      const uint4 gu = sg[gidx], g2u = sg2[gidx], gbu = sgb[gidx];
      S0 = fdot2(a0, one, S0); S0 = fdot2(a1, one, S0);
      S0 = fdot2(a2, one, S0); S0 = fdot2(a3, one, S0);
      S1 = fdot2(a0, a0, S1); S1 = fdot2(a1, a1, S1);
      S1 = fdot2(a2, a2, S1); S1 = fdot2(a3, a3, S1);
      const h2 g0 = bch(gu.x), g1p = bch(gu.y), g2p = bch(gu.z), g3p = bch(gu.w);
      Sa = fdot2(g0, a0, Sa); Sa = fdot2(g1p, a1, Sa);
      Sa = fdot2(g2p, a2, Sa); Sa = fdot2(g3p, a3, Sa);
      const h2 G0 = bch(g2u.x), G1 = bch(g2u.y), G2 = bch(g2u.z), G3 = bch(g2u.w);
      Sb = fdot2(G0, a0, Sb); Sb = fdot2(G1, a1, Sb);
      Sb = fdot2(G2, a2, Sb); Sb = fdot2(G3, a3, Sb);
      Sc = fdot2(G0, a0 * a0, Sc); Sc = fdot2(G1, a1 * a1, Sc);
      Sc = fdot2(G2, a2 * a2, Sc); Sc = fdot2(G3, a3 * a3, Sc);
      const h2 Q0 = bch(gbu.x), Q1 = bch(gbu.y), Q2 = bch(gbu.z), Q3 = bch(gbu.w);
      Sd = fdot2(Q0, a0, Sd); Sd = fdot2(Q1, a1, Sd);
      Sd = fdot2(Q2, a2, Sd); Sd = fdot2(Q3, a3, Sd);
      union { h2 p[4]; half8 v; } ua;
      ua.p[0] = a0; ua.p[1] = a1; ua.p[2] = a2; ua.p[3] = a3;
      sacc = __builtin_amdgcn_mfma_f32_16x16x32_f16(
          ua.v, __builtin_bit_cast(half8, bu), sacc, 0, 0, 0);
      uint4 xw;
      xw.x = hbits(a0); xw.y = hbits(a1); xw.z = hbits(a2); xw.w = hbits(a3);
      *(uint4*)&xl[w][col * 133 + kg * 4 + ks * 16] = xw;
    }
#pragma unroll
    for (int m = 16; m < 64; m <<= 1) {
      S0 += __shfl_xor(S0, m, 64); S1 += __shfl_xor(S1, m, 64);
      Sa += __shfl_xor(Sa, m, 64); Sb += __shfl_xor(Sb, m, 64);
      Sc += __shfl_xor(Sc, m, 64); Sd += __shfl_xor(Sd, m, 64);
    }
    if (lane < 16) {
      stat[w][lane][0] = S0; stat[w][lane][1] = S1; stat[w][lane][2] = Sa;
      stat[w][lane][3] = Sb; stat[w][lane][4] = Sc; stat[w][lane][5] = Sd;
    }
    sred[w][lane] = sacc;
    __syncthreads();
    f32x4 full = sred[0][lane];
    full += sred[1][lane]; full += sred[2][lane]; full += sred[3][lane];
    float T0 = 0, T1v = 0, Ta = 0, Tb = 0, Tc = 0, Td = 0;
#pragma unroll
    for (int ww = 0; ww < 4; ww++) {
      T0 += stat[ww][col][0]; T1v += stat[ww][col][1]; Ta += stat[ww][col][2];
      Tb += stat[ww][col][3]; Tc += stat[ww][col][4]; Td += stat[ww][col][5];
    }
    const float m1 = T0 * (1.f / D);
    const float rs1 = rsqrtf(T1v * (1.f / D) - m1 * m1 + EPS_LN);
    const float m2 = (rs1 * (Ta - m1 * Sg1) + Sb1) * (1.f / D);
    const float sxn2 = rs1 * rs1 * Tc + 2.f * rs1 * (Td - m1 * rs1 * Tb) +
                       (Sbbc - 2.f * m1 * rs1 * Sgbc + m1 * m1 * rs1 * rs1 * Sggc);
    const float rs2 = rsqrtf(sxn2 * (1.f / D) - m2 * m2 + EPS_LN);
    const float v1 = rs1 * rs2, v2 = v1 * m1, v3 = rs2, v4 = rs2 * m2;
    float ap_[4];
#pragma unroll
    for (int j = 0; j < 4; j++) {
      const int rj = kg * 4 + j;
      const float w1 = __shfl(v1, rj, 64), w2 = __shfl(v2, rj, 64);
      const float w3 = __shfl(v3, rj, 64), w4 = __shfl(v4, rj, 64);
      const float s = w1 * full[j] - w2 * c3 + w3 * c2 - w4 * c4 + c5;
      const float e = __expf(s);
      ap_[j] = e * w1;
      if (w == 0) { dh0 += e; dh1 += e * w3; dh2 += e * w2; dh3 += e * w4; }
    }
    union { h2 p[4]; half8 v; } ap;
    ap.p[0] = pkh(ap_[0], ap_[1]); ap.p[1] = pkh(ap_[2], ap_[3]);
    ap.p[2] = bch(0u); ap.p[3] = bch(0u);
    const unsigned int* xw = xl[w];
#pragma unroll
    for (int c = 0; c < 16; c++) {
      const int bidx = c * 8 + (col >> 1);
      const unsigned int r0w = xw[(kg * 4 + 0) * 133 + bidx];
      const unsigned int r1w = xw[(kg * 4 + 1) * 133 + bidx];
      const unsigned int r2w = xw[(kg * 4 + 2) * 133 + bidx];
      const unsigned int r3w = xw[(kg * 4 + 3) * 133 + bidx];
      union { unsigned int u[4]; half8 v; } bb;
      bb.u[0] = ((r0w >> sh) & 0xffffu) | (((r1w >> sh) & 0xffffu) << 16);
      bb.u[1] = ((r2w >> sh) & 0xffffu) | (((r3w >> sh) & 0xffffu) << 16);
      bb.u[2] = 0u; bb.u[3] = 0u;
      accpv[c] = __builtin_amdgcn_mfma_f32_16x16x32_f16(ap.v, bb.v, accpv[c], 0, 0, 0);
    }
    __syncthreads();
  }
  if (w == 0) {
#pragma unroll
    for (int m = 16; m < 64; m <<= 1) {
      dh0 += __shfl_xor(dh0, m, 64); dh1 += __shfl_xor(dh1, m, 64);
      dh2 += __shfl_xor(dh2, m, 64); dh3 += __shfl_xor(dh3, m, 64);
    }
    if (lane < 16) {
      const int b = blockIdx.x / bpb;
      float* cb = Cbuf + (b * 16 + lane) * 4;
      atomicAdd(cb + 0, dh0); atomicAdd(cb + 1, dh1);
      atomicAdd(cb + 2, dh2); atomicAdd(cb + 3, dh3);
    }
  }
  float* po = part + ((size_t)blockIdx.x * 16) * 1024 + w * 256;
#pragma unroll
  for (int c = 0; c < 16; c++) {
#pragma unroll
    for (int reg = 0; reg < 4; reg++) {
      const int h = kg * 4 + reg;
      po[(size_t)h * 1024 + c * 16 + col] = accpv[c][reg];
    }
  }
}

// ---------- reduce partials + normalize + affine V-input assembly ----------
__global__ void k_reduce(const float* __restrict__ part, const float* __restrict__ Cbuf,
                         const float* __restrict__ g1, const float* __restrict__ b1,
                         const float* __restrict__ vg, const float* __restrict__ vb,
                         float* __restrict__ vpool, int bpb) {
  const int b = blockIdx.x >> 4, h = blockIdx.x & 15;
  const int t = threadIdx.x, d = t * 4;
  float4 a = make_float4(0.f, 0.f, 0.f, 0.f);
  for (int k = 0; k < bpb; k++) {
    const float4 p =
        *(const float4*)(part + ((size_t)((b * bpb + k) * 16 + h)) * 1024 + d);
    a.x += p.x; a.y += p.y; a.z += p.z; a.w += p.w;
  }
  const float4 C = ((const float4*)Cbuf)[b * 16 + h];  // den, C1, C2, C3 (unnorm)
  const float inv = 1.f / C.x;
  const float C1n = C.y * inv, C2n = C.z * inv, C3n = C.w * inv;
  const float4 gv = ((const float4*)g1)[t], bv = ((const float4*)b1)[t];
  const float4 vgv = ((const float4*)vg)[t], vbv = ((const float4*)vb)[t];
  float4 o;
  o.x = vgv.x * (gv.x * (a.x * inv - C2n) + bv.x * C1n - C3n) + vbv.x;
  o.y = vgv.y * (gv.y * (a.y * inv - C2n) + bv.y * C1n - C3n) + vbv.y;
  o.z = vgv.z * (gv.z * (a.z * inv - C2n) + bv.z * C1n - C3n) + vbv.z;
  o.w = vgv.w * (gv.w * (a.w * inv - C2n) + bv.w * C1n - C3n) + vbv.w;
  *(float4*)(vpool + ((size_t)b * H + h) * D + d) = o;
}

// ---------- out[b][j] = W[j,:] . src[b, head-sliced] + bias[j] ----------
__global__ void k_proj8(const float* __restrict__ src, const float* __restrict__ W,
                        const float* __restrict__ bias, float* __restrict__ out,
                        int bstride, int hstride) {
  const int j = blockIdx.x, lane = threadIdx.x;
  const int h = j >> 6;
  const float4* wr = (const float4*)(W + (size_t)j * D);
  float acc[8];
#pragma unroll
  for (int b = 0; b < 8; b++) acc[b] = 0.f;
#pragma unroll
  for (int k = 0; k < 4; k++) {
    const float4 w4 = wr[lane + 64 * k];
#pragma unroll
    for (int b = 0; b < 8; b++) {
      const float4 s4 =
          ((const float4*)(src + (size_t)b * bstride + (size_t)h * hstride))[lane + 64 * k];
      acc[b] = fmaf(w4.x, s4.x, acc[b]); acc[b] = fmaf(w4.y, s4.y, acc[b]);
      acc[b] = fmaf(w4.z, s4.z, acc[b]); acc[b] = fmaf(w4.w, s4.w, acc[b]);
    }
  }
#pragma unroll
  for (int b = 0; b < 8; b++) acc[b] = wred_sum(acc[b]);
  if (!lane) {
    const float bj = bias[j];
#pragma unroll
    for (int b = 0; b < 8; b++) out[(size_t)b * D + j] = acc[b] + bj;
  }
}

extern "C" void kernel_launch(void* const* d_in, const int* in_sizes, int n_in,
                              void* d_out, int out_size, void* d_ws, size_t ws_size,
                              hipStream_t stream) {
  const float* x = (const float*)d_in[0];
  const float* query = (const float*)d_in[1];
  const float* norm_g = (const float*)d_in[2];
  const float* norm_b = (const float*)d_in[3];
  const float* nq_g = (const float*)d_in[4];
  const float* nq_b = (const float*)d_in[5];
  const float* nk_g = (const float*)d_in[6];
  const float* nk_b = (const float*)d_in[7];
  const float* nv_g = (const float*)d_in[8];
  const float* nv_b = (const float*)d_in[9];
  const float* no_g = (const float*)d_in[10];
  const float* no_b = (const float*)d_in[11];
  const float* Wq = (const float*)d_in[12];
  const float* bq = (const float*)d_in[13];
  const float* Wk = (const float*)d_in[14];
  // d_in[15] = bk: constant per (b,h) in scores -> cancels in softmax
  const float* Wv = (const float*)d_in[16];
  const float* bv = (const float*)d_in[17];
  const float* Wo = (const float*)d_in[18];
  const float* bo = (const float*)d_in[19];

  char* ws = (char*)d_ws;
  float* qv = (float*)(ws + 0);           // 4 KB
  uint4* B1 = (uint4*)(ws + 4096);        // 32 KB
  uint4* gt = (uint4*)(ws + 36864);       // 2 KB
  uint4* g2t = (uint4*)(ws + 38912);      // 2 KB
  uint4* gbt = (uint4*)(ws + 40960);      // 2 KB
  float* hc = (float*)(ws + 43008);       // 256 B
  float* sconst = (float*)(ws + 43264);   // 64 B
  float* Cbuf = (float*)(ws + 43328);     // 2 KB
  float* vpool = (float*)(ws + 45568);    // 512 KB
  float* av = (float*)(ws + 569856);      // 32 KB
  float* yb = (float*)(ws + 602624);      // 32 KB
  float* part = (float*)(ws + 635904);    // NBLK*16*1024*4

  int NBLK = 512;
  if (635904ull + (size_t)NBLK * 16 * 1024 * 4 > ws_size) NBLK = 256;
  const int niter = NROWS / (16 * NBLK);
  const int bpb = NBLK / B;

  k_qln<<<256, 256, 0, stream>>>(query, nq_g, nq_b, Wq, bq, qv);
  k_prep0G<<<1, 256, 0, stream>>>(norm_g, norm_b, sconst, gt, g2t, gbt, hc, Cbuf);
  k_uprep64<<<64, 256, 0, stream>>>(qv, Wk, norm_g, norm_b, nk_g, nk_b, hc, B1);
  k_fused<<<NBLK, 256, 0, stream>>>(x, B1, gt, g2t, gbt, hc, sconst, part, Cbuf,
                                    niter, bpb);
  k_reduce<<<128, 256, 0, stream>>>(part, Cbuf, norm_g, norm_b, nv_g, nv_b, vpool, bpb);
  k_proj8<<<1024, 64, 0, stream>>>(vpool, Wv, bv, av, H * D, D);  // V-proj on pooled
  k_proj8<<<1024, 64, 0, stream>>>(av, Wo, bo, yb, D, 0);         // O-proj
  k_ln256<<<8, 256, 0, stream>>>(yb, no_g, no_b, (float*)d_out);
}